// Round 8
// baseline (224.964 us; speedup 1.0000x reference)
//
#include <hip/hip_runtime.h>
#include <hip/hip_bf16.h>

// ---------------------------------------------------------------------------
// SimpleSelfAttention: out = softmax((xWq^T+bq)(xWk^T+bk)^T / 32) (xWv^T+bv)
// B=4, S=2048, E=1024, fp32 in/out. Internally bf16 MFMA, fp32 accum.
//
// gemmW: tile 256x128, BK=64, 8 waves (512 thr), wave out 128x32.
// 3 K-tile LDS buffers (144 KB, 1 block/CU), stage-2-ahead via global_load_lds
// in 3 half-tiles/tile (A0+B at P0: 4 loads/thr, A1 at P1: 2 loads/thr).
// 2 phases/tile, cross-phase frag prefetch: phase p issues ds_reads for p+1,
// so lgkmcnt(0) at each phase start waits reads that had a full MFMA cluster
// to land. ONE s_barrier/tile at P1: after own vmcnt(4) (counted, never 0
// mid-loop) -> all waves' t+1 staging confirmed before any t+1 frag read,
// and all buf-b reads retired before buf-b is re-staged (at t+1's P0).
// Swizzle: 16B chunk c of row r (128-B rows) at c ^ (r&7); 2-way = free.
// XCD swizzle: id2 = (id%8)*(nwg/8) + id/8 (nwg%8==0 for all grids).
//
// Memory plan (round-7's, passing): no final memcpy.
//   ws: Q@0 | K@8M1 | P@16M1 ; V over dead Q, VT over dead K (post-scores)
//   d_out scratch: xb@0 (16MB) | Wb@8M1 (6MB), dead before PV writes d_out.
// ---------------------------------------------------------------------------

typedef __attribute__((ext_vector_type(8))) short bf16x8;
typedef __attribute__((ext_vector_type(4))) float f32x4;

#define DEVI static __device__ __forceinline__

DEVI short to_bf16(float f) {
    unsigned u = __builtin_bit_cast(unsigned, f);
    u += 0x7fffu + ((u >> 16) & 1u);          // RNE (finite/normal inputs)
    return (short)(u >> 16);
}
DEVI float from_bf16(short s) {
    return __builtin_bit_cast(float, (unsigned)((unsigned short)s) << 16);
}

DEVI void gload_lds16(const short* g, short* l) {
    __builtin_amdgcn_global_load_lds(
        (const __attribute__((address_space(1))) void*)g,
        (__attribute__((address_space(3))) void*)l, 16, 0, 0);
}

// C[z][M][N] = scale * A[z].B[z]^T (+ bias_z[n]). A,B bf16 K-major.
// Grid: dim3(nwg, NZ); nwg = (M/256)*(N/128), gx = N/128. K % 64 == 0, K>=192.
template<int BIAS, typename TOUT>
__global__ __launch_bounds__(512, 2)
void gemmW(const short* __restrict__ A, long lda, long bsA,
           const short* __restrict__ B, long ldb, long bsB,
           const float* __restrict__ bi0, const float* __restrict__ bi1,
           const float* __restrict__ bi2,
           TOUT* __restrict__ c0, TOUT* __restrict__ c1, TOUT* __restrict__ c2,
           long ldc, long bsC, int K, float scale, int gx)
{
    __shared__ __align__(16) short As[3 * 16384];   // [buf][half][128][64]
    __shared__ __align__(16) short Bs[3 * 8192];    // [buf][128][64]

    const int tid = threadIdx.x;
    const int z = blockIdx.y;

    // XCD-aware bijective swizzle (nwg % 8 == 0 for all our grids)
    const int nwg = gridDim.x;
    const int id = blockIdx.x;
    const int id2 = (id & 7) * (nwg >> 3) + (id >> 3);
    const long m0 = (long)(id2 / gx) * 256;
    const long n0 = (long)(id2 % gx) * 128;

    const short* Ab = A + (long)z * bsA + m0 * lda;
    const short* Bb = B + (long)z * bsB + n0 * ldb;

    const int wv = tid >> 6;
    const int wm = wv >> 2;            // 0..1 : A row-half
    const int wn = wv & 3;             // 0..3 : 32-col strip of BN=128
    const int lane = tid & 63;
    const int lrow = lane & 15;
    const int q = lane >> 4;           // k-quarter (8 contiguous k elems)

    const int NT = K >> 6;             // BK=64

    // stage one A half-tile (128x64) of K-tile t into buffer bb
    auto stA = [&](int t, int bb, int h) {
        const long k0 = (long)t * 64;
        #pragma unroll
        for (int i = 0; i < 2; ++i) {
            int s = i * 512 + tid;                 // 0..1023
            int row = s >> 3, cc = s & 7;
            int src = cc ^ (row & 7);
            gload_lds16(Ab + (long)(h * 128 + row) * lda + k0 + src * 8,
                        &As[bb * 16384 + h * 8192 + s * 8]);
        }
    };
    // stage the B tile (128x64) of K-tile t into buffer bb
    auto stB = [&](int t, int bb) {
        const long k0 = (long)t * 64;
        #pragma unroll
        for (int i = 0; i < 2; ++i) {
            int s = i * 512 + tid;
            int row = s >> 3, cc = s & 7;
            int src = cc ^ (row & 7);
            gload_lds16(Bb + (long)row * ldb + k0 + src * 8,
                        &Bs[bb * 8192 + s * 8]);
        }
    };

    // frag loads (ds_read_b128); half: 0 -> m-frags 0-3, 1 -> 4-7
    auto ldA = [&](bf16x8 (&dst)[4][2], int bb, int half) {
        #pragma unroll
        for (int m = 0; m < 4; ++m) {
            #pragma unroll
            for (int kk = 0; kk < 2; ++kk) {
                int rl = (half * 4 + m) * 16 + lrow;       // 0..127
                int ch = (kk * 4 + q) ^ (rl & 7);
                dst[m][kk] = *(const bf16x8*)
                    &As[bb * 16384 + wm * 8192 + rl * 64 + ch * 8];
            }
        }
    };
    auto ldB = [&](bf16x8 (&dst)[2][2], int bb) {
        #pragma unroll
        for (int n = 0; n < 2; ++n) {
            #pragma unroll
            for (int kk = 0; kk < 2; ++kk) {
                int rb = wn * 32 + n * 16 + lrow;          // 0..127
                int ch = (kk * 4 + q) ^ (rb & 7);
                dst[n][kk] = *(const bf16x8*)&Bs[bb * 8192 + rb * 64 + ch * 8];
            }
        }
    };

    f32x4 acc[8][2] = {};
    bf16x8 afA[4][2], afB[4][2], bfE[2][2], bfO[2][2];

    auto mm = [&](bf16x8 (&af)[4][2], bf16x8 (&bf)[2][2], int half) {
        __builtin_amdgcn_s_setprio(1);
        #pragma unroll
        for (int m = 0; m < 4; ++m)
            #pragma unroll
            for (int n = 0; n < 2; ++n)
                #pragma unroll
                for (int kk = 0; kk < 2; ++kk)
                    acc[half * 4 + m][n] = __builtin_amdgcn_mfma_f32_16x16x32_bf16(
                        af[m][kk], bf[n][kk], acc[half * 4 + m][n], 0, 0, 0);
        __builtin_amdgcn_s_setprio(0);
    };

    // bfU: B-frags of tile t (in regs); bfL: loaded here for tile t+1
    auto tile = [&](int t, int bb0, int bb1, int bb2,
                    bf16x8 (&bfU)[2][2], bf16x8 (&bfL)[2][2]) {
        const bool pre2 = (t + 2 < NT), pre1 = (t + 1 < NT);
        // ---- Phase 0 ----
        asm volatile("s_waitcnt lgkmcnt(0)" ::: "memory");   // afA,bfU landed
        __builtin_amdgcn_sched_barrier(0);
        if (pre2) { stA(t + 2, bb2, 0); stB(t + 2, bb2); }   // 4 loads
        ldA(afB, bb0, 1);                                    // 8 ds_reads
        mm(afA, bfU, 0);
        // ---- Phase 1 ----
        asm volatile("s_waitcnt lgkmcnt(0)" ::: "memory");   // afB landed
        __builtin_amdgcn_sched_barrier(0);
        if (pre2) asm volatile("s_waitcnt vmcnt(4)" ::: "memory");  // t+1 staged
        else      asm volatile("s_waitcnt vmcnt(0)" ::: "memory");
        __builtin_amdgcn_sched_barrier(0);
        __builtin_amdgcn_s_barrier();    // all waves: t+1 staged, buf bb0 reads done
        if (pre2) stA(t + 2, bb2, 1);                        // 2 loads
        if (pre1) { ldA(afA, bb1, 0); ldB(bfL, bb1); }       // 12 ds_reads
        mm(afB, bfU, 1);
    };

    // prologue: stage tiles 0,1 fully (6+6 loads)
    stA(0, 0, 0); stB(0, 0); stA(0, 0, 1);
    stA(1, 1, 0); stB(1, 1); stA(1, 1, 1);
    asm volatile("s_waitcnt vmcnt(6)" ::: "memory");         // tile 0 landed
    __builtin_amdgcn_sched_barrier(0);
    __builtin_amdgcn_s_barrier();
    ldA(afA, 0, 0); ldB(bfE, 0);

    int b = 0;
    for (int t = 0; t < NT; t += 2) {
        int B1 = b + 1; if (B1 >= 3) B1 -= 3;
        int B2 = b + 2; if (B2 >= 3) B2 -= 3;
        tile(t,     b,  B1, B2, bfE, bfO);
        tile(t + 1, B1, B2, b,  bfO, bfE);
        b += 2; if (b >= 3) b -= 3;
    }

    // epilogue: C/D layout (verified m89): col = lane&15, row = q*4 + reg
    const float* bias = (z == 0) ? bi0 : (z == 1) ? bi1 : bi2;
    TOUT* Cb = (((z == 0) ? c0 : (z == 1) ? c1 : c2) + (long)z * bsC)
               + m0 * ldc + n0;
    #pragma unroll
    for (int m = 0; m < 8; ++m) {
        #pragma unroll
        for (int n = 0; n < 2; ++n) {
            #pragma unroll
            for (int r = 0; r < 4; ++r) {
                int row = wm * 128 + m * 16 + q * 4 + r;
                int col = wn * 32 + n * 16 + lrow;
                float v = acc[m][n][r] * scale;
                if constexpr (BIAS == 1) v += bias[n0 + col];
                if constexpr (sizeof(TOUT) == 2)
                    Cb[(long)row * ldc + col] = to_bf16(v);
                else
                    Cb[(long)row * ldc + col] = v;
            }
        }
    }
}

// fp32 -> bf16, 8 elems/thread
__global__ __launch_bounds__(256)
void cvt_f32_bf16(const float* __restrict__ src, short* __restrict__ dst, int n8)
{
    int i = blockIdx.x * 256 + threadIdx.x;
    if (i < n8) {
        float4 a = ((const float4*)src)[2 * i];
        float4 b = ((const float4*)src)[2 * i + 1];
        bf16x8 o = { to_bf16(a.x), to_bf16(a.y), to_bf16(a.z), to_bf16(a.w),
                     to_bf16(b.x), to_bf16(b.y), to_bf16(b.z), to_bf16(b.w) };
        *(bf16x8*)&dst[i * 8] = o;
    }
}

// three fp32 srcs -> contiguous bf16 dst (blockIdx.y selects src)
__global__ __launch_bounds__(256)
void cvt3_f32_bf16(const float* __restrict__ s0, const float* __restrict__ s1,
                   const float* __restrict__ s2, short* __restrict__ dst, int n8)
{
    int zz = blockIdx.y;
    const float* src = (zz == 0) ? s0 : (zz == 1) ? s1 : s2;
    int i = blockIdx.x * 256 + threadIdx.x;
    if (i < n8) {
        float4 a = ((const float4*)src)[2 * i];
        float4 b = ((const float4*)src)[2 * i + 1];
        bf16x8 o = { to_bf16(a.x), to_bf16(a.y), to_bf16(a.z), to_bf16(a.w),
                     to_bf16(b.x), to_bf16(b.y), to_bf16(b.z), to_bf16(b.w) };
        *(bf16x8*)&dst[(long)zz * n8 * 8 + i * 8] = o;
    }
}

// In-place row softmax over bf16 rows of length 2048. One block/row.
__global__ __launch_bounds__(256)
void softmax_rows(short* __restrict__ S, int ncols)
{
    const long row = blockIdx.x;
    short* p = S + row * (long)ncols;
    const int t = threadIdx.x;

    union { bf16x8 v; short s[8]; } u;
    u.v = *(const bf16x8*)&p[t * 8];
    float f[8];
    float m = -3.0e38f;
    #pragma unroll
    for (int j = 0; j < 8; ++j) { f[j] = from_bf16(u.s[j]); m = fmaxf(m, f[j]); }
    #pragma unroll
    for (int off = 32; off > 0; off >>= 1) m = fmaxf(m, __shfl_xor(m, off));

    __shared__ float red[8];
    const int wave = t >> 6;
    if ((t & 63) == 0) red[wave] = m;
    __syncthreads();
    m = fmaxf(fmaxf(red[0], red[1]), fmaxf(red[2], red[3]));

    float sum = 0.f;
    #pragma unroll
    for (int j = 0; j < 8; ++j) { f[j] = __expf(f[j] - m); sum += f[j]; }
    #pragma unroll
    for (int off = 32; off > 0; off >>= 1) sum += __shfl_xor(sum, off);
    if ((t & 63) == 0) red[4 + wave] = sum;
    __syncthreads();
    sum = red[4] + red[5] + red[6] + red[7];

    const float inv = 1.0f / sum;
    #pragma unroll
    for (int j = 0; j < 8; ++j) u.s[j] = to_bf16(f[j] * inv);
    *(bf16x8*)&p[t * 8] = u.v;
}

// dst[z][c][r] = src[z][r][c], bf16, 32x32 LDS tiles.
__global__ __launch_bounds__(256)
void transpose_bf16(const short* __restrict__ src, short* __restrict__ dst, int R, int Cc)
{
    __shared__ short tl[32][33];
    const long zoff = (long)blockIdx.z * R * Cc;
    const int r0 = blockIdx.x * 32;
    const int c0 = blockIdx.y * 32;
    const int tid = threadIdx.x;
    #pragma unroll
    for (int i = 0; i < 4; ++i) {
        int qq = tid + 256 * i;
        int r = qq >> 5, c = qq & 31;
        tl[r][c] = src[zoff + (long)(r0 + r) * Cc + c0 + c];
    }
    __syncthreads();
    #pragma unroll
    for (int i = 0; i < 4; ++i) {
        int qq = tid + 256 * i;
        int r = qq >> 5, c = qq & 31;
        dst[zoff + (long)(c0 + r) * R + r0 + c] = tl[c][r];
    }
}

extern "C" void kernel_launch(void* const* d_in, const int* in_sizes, int n_in,
                              void* d_out, int out_size, void* d_ws, size_t ws_size,
                              hipStream_t stream)
{
    (void)in_sizes; (void)n_in; (void)out_size; (void)ws_size;

    const float* x  = (const float*)d_in[0];
    const float* Wq = (const float*)d_in[1];
    const float* bq = (const float*)d_in[2];
    const float* Wk = (const float*)d_in[3];
    const float* bk = (const float*)d_in[4];
    const float* Wv = (const float*)d_in[5];
    const float* bv = (const float*)d_in[6];
    float* out = (float*)d_out;

    const int S = 2048, E = 1024;
    const long M1 = 1024l * 1024;

    // ws regions (shorts)
    short* w  = (short*)d_ws;
    short* Q  = w;                  // [4][2048][1024]  (16MB)
    short* Kb = w + 8 * M1;         // [4][2048][1024]  (16MB)
    short* P  = w + 16 * M1;        // [4][2048][2048]  (32MB)
    short* V  = w;                  // [4][2048][1024] over dead Q (post-scores)
    short* VT = w + 8 * M1;         // [4][1024][2048] over dead K (post-scores)

    // d_out scratch (dead before PV writes d_out)
    short* dows = (short*)d_out;
    short* xb = dows;               // [8192][1024] bf16 (16MB)
    short* Wb = dows + 8 * M1;      // Wq,Wk,Wv bf16 (3 x 2MB)

    dim3 blk(256), blkg(512);

    // 1. convert inputs to bf16
    cvt_f32_bf16<<<dim3(4096), blk, 0, stream>>>(x, xb, (int)M1);
    cvt3_f32_bf16<<<dim3(512, 3), blk, 0, stream>>>(Wq, Wk, Wv, Wb, (int)(M1 / 8));

    // 2. Q,K projections (M=8192,N=1024,K=1024): nwg=32*8=256, z=2
    gemmW<1, short><<<dim3(256, 2), blkg, 0, stream>>>(
        xb, E, 0, Wb, E, M1, bq, bk, nullptr,
        Q, Kb, nullptr, E, 0, E, 1.0f, 8);

    // 3. scores: P[z] = Q[z] K[z]^T / 32 (M=N=2048,K=1024): nwg=8*16=128, z=4
    gemmW<0, short><<<dim3(128, 4), blkg, 0, stream>>>(
        Q, E, 2 * M1, Kb, E, 2 * M1, nullptr, nullptr, nullptr,
        P, P, P, S, 4 * M1, E, 0.03125f, 16);

    // 4. V projection into dead Q region: nwg=256, z=1
    gemmW<1, short><<<dim3(256, 1), blkg, 0, stream>>>(
        xb, E, 0, Wb + 2 * M1, E, 0, bv, nullptr, nullptr,
        V, nullptr, nullptr, E, 0, E, 1.0f, 8);

    // 5. VT[z] = V[z]^T ([1024][2048]) into dead K region
    transpose_bf16<<<dim3(S / 32, E / 32, 4), blk, 0, stream>>>(V, VT, S, E);

    // 6. softmax rows in place
    softmax_rows<<<dim3(4 * S), blk, 0, stream>>>(P, S);

    // 7. out[z] = P[z] VT[z]^T (M=2048,N=1024,K=2048): nwg=8*8=64, z=4, fp32
    gemmW<0, float><<<dim3(64, 4), blkg, 0, stream>>>(
        P, S, 4 * M1, VT, S, 2 * M1, nullptr, nullptr, nullptr,
        out, out, out, E, 2 * M1, S, 1.0f, 8);
}

// Round 9
// 187.042 us; speedup vs baseline: 1.2027x; 1.2027x over previous
//
#include <hip/hip_runtime.h>
#include <hip/hip_bf16.h>

// ---------------------------------------------------------------------------
// SimpleSelfAttention: out = softmax((xWq^T+bq)(xWk^T+bk)^T / 32) (xWv^T+bv)
// B=4, S=2048, E=1024, fp32 in/out. Internally bf16 MFMA, fp32 accum.
//
// GEMM core (gemm8, R6-proven): tile 128x256, 4 waves (256 thr), wave output
// 128x64 (MF=8, NF=4). 3 LDS buffers, BK=32: tile t+2 staged via
// global_load_lds (6 loads/thread) into buf (t+2)%3 during tile t -- stage
// target is never live. Barrier per tile: lgkmcnt(0) + vmcnt(6) (counted,
// never 0 mid-loop) + s_barrier. Swizzle: 16B chunk c of row r at
// c ^ ((r>>1)&3) (2-way bank aliasing = free).
//
// Pipeline (VT computed directly as GEMM; no transpose, no final memcpy):
//   ws: Q@0 (16MB) | K@8M1 (16MB) | P@16M1 (32MB) ; VT@8M1 over dead K
//   d_out scratch: xb@0 (16MB) | Wb@8M1 (6MB)  [last read by VT-GEMM]
//   cvt -> QK proj (z=2) -> scores -> VT = Wv xb^T + bv (row bias, z=4)
//       -> softmax -> PV (fp32 direct to d_out)
// ---------------------------------------------------------------------------

typedef __attribute__((ext_vector_type(8))) short bf16x8;
typedef __attribute__((ext_vector_type(4))) float f32x4;

#define DEVI static __device__ __forceinline__

DEVI short to_bf16(float f) {
    unsigned u = __builtin_bit_cast(unsigned, f);
    u += 0x7fffu + ((u >> 16) & 1u);          // RNE (finite/normal inputs)
    return (short)(u >> 16);
}
DEVI float from_bf16(short s) {
    return __builtin_bit_cast(float, (unsigned)((unsigned short)s) << 16);
}

DEVI void gload_lds16(const short* g, short* l) {
    __builtin_amdgcn_global_load_lds(
        (const __attribute__((address_space(1))) void*)g,
        (__attribute__((address_space(3))) void*)l, 16, 0, 0);
}

// C[z][M][N] = scale * A[z].B[z]^T (+ bias). A,B bf16 K-major.
// BIAS: 0=none, 1=col bias b_z[n] (z-selected), 2=row bias b0[m] (all z).
// Output pointer selected by z from {c0,c1,c2}, plus z*bsC (batched: c0=c1=c2).
template<int BM, int BN, int BIAS, typename TOUT>
__global__ __launch_bounds__(256, 2)
void gemm8(const short* __restrict__ A, long lda, long bsA,
           const short* __restrict__ B, long ldb, long bsB,
           const float* __restrict__ b0, const float* __restrict__ b1,
           const float* __restrict__ b2,
           TOUT* __restrict__ c0, TOUT* __restrict__ c1, TOUT* __restrict__ c2,
           long ldc, long bsC, int K, float scale)
{
    constexpr int MF = BM / 16;        // m-frags per wave (wave spans all BM rows)
    constexpr int NF = BN / 64;        // n-frags per wave (wave cols = BN/4)
    constexpr int RA = (BM * 32) / (8 * 256);   // A stage loads per thread
    constexpr int RB = (BN * 32) / (8 * 256);   // B stage loads per thread

    __shared__ __align__(16) short As[3 * BM * 32];
    __shared__ __align__(16) short Bs[3 * BN * 32];

    const int tid = threadIdx.x;
    const int z = blockIdx.z;
    const long m0 = (long)blockIdx.y * BM;
    const long n0 = (long)blockIdx.x * BN;
    const short* Ab = A + (long)z * bsA + m0 * lda;
    const short* Bb = B + (long)z * bsB + n0 * ldb;

    const int wn = tid >> 6;           // wave = one 128x64 column strip
    const int lane = tid & 63;
    const int lrow = lane & 15;
    const int q = lane >> 4;           // k-quarter (8 contiguous k elems)

    const int NT = K >> 5;             // BK=32

    auto stage = [&](int t, int b) {
        const long koff = (long)t * 32;
        #pragma unroll
        for (int i = 0; i < RA; ++i) {
            int s = i * 256 + tid;
            int row = s >> 2;
            int c = (s & 3) ^ ((row >> 1) & 3);
            gload_lds16(Ab + (long)row * lda + koff + c * 8,
                        &As[b * BM * 32 + s * 8]);
        }
        #pragma unroll
        for (int i = 0; i < RB; ++i) {
            int s = i * 256 + tid;
            int row = s >> 2;
            int c = (s & 3) ^ ((row >> 1) & 3);
            gload_lds16(Bb + (long)row * ldb + koff + c * 8,
                        &Bs[b * BN * 32 + s * 8]);
        }
    };

    f32x4 acc[MF][NF] = {};

    stage(0, 0);
    stage(1, 1);
    asm volatile("s_waitcnt vmcnt(6)" ::: "memory");
    __builtin_amdgcn_sched_barrier(0);
    __builtin_amdgcn_s_barrier();

    int b = 0;
    for (int t = 0; t < NT; ++t) {
        const short* Asb = &As[b * BM * 32];
        const short* Bsb = &Bs[b * BN * 32];

        bf16x8 bfr[NF];
        #pragma unroll
        for (int n = 0; n < NF; ++n) {
            int row = wn * 64 + n * 16 + lrow;
            int p = q ^ ((row >> 1) & 3);
            bfr[n] = *(const bf16x8*)&Bsb[row * 32 + p * 8];
        }
        bf16x8 af[MF];
        #pragma unroll
        for (int m = 0; m < MF; ++m) {
            int row = m * 16 + lrow;
            int p = q ^ ((row >> 1) & 3);
            af[m] = *(const bf16x8*)&Asb[row * 32 + p * 8];
        }

        if (t + 2 < NT) {
            int tb = b + 2; if (tb >= 3) tb -= 3;
            stage(t + 2, tb);
        }

        __builtin_amdgcn_s_setprio(1);
        #pragma unroll
        for (int m = 0; m < MF; ++m)
            #pragma unroll
            for (int n = 0; n < NF; ++n)
                acc[m][n] = __builtin_amdgcn_mfma_f32_16x16x32_bf16(
                    af[m], bfr[n], acc[m][n], 0, 0, 0);
        __builtin_amdgcn_s_setprio(0);

        if (t < NT - 1) {
            // reads of buf b retired -> next tile may stage over it;
            // tile t+1's data landed (only t+2's 6 loads stay in flight)
            asm volatile("s_waitcnt lgkmcnt(0)" ::: "memory");
            asm volatile("s_waitcnt vmcnt(6)" ::: "memory");
            __builtin_amdgcn_sched_barrier(0);
            __builtin_amdgcn_s_barrier();
        }
        ++b; if (b == 3) b = 0;
    }

    // C/D layout (verified m89): col = lane&15, row = (lane>>4)*4 + reg
    const float* bias = (BIAS == 2) ? b0
                      : ((z == 0) ? b0 : (z == 1) ? b1 : b2);
    TOUT* Cz = ((z == 0) ? c0 : (z == 1) ? c1 : c2) + (long)z * bsC;
    TOUT* Cb = Cz + m0 * ldc + n0;
    #pragma unroll
    for (int m = 0; m < MF; ++m) {
        #pragma unroll
        for (int n = 0; n < NF; ++n) {
            #pragma unroll
            for (int r = 0; r < 4; ++r) {
                int row = m * 16 + q * 4 + r;
                int col = wn * 64 + n * 16 + lrow;
                float v = acc[m][n][r] * scale;
                if constexpr (BIAS == 1) v += bias[n0 + col];
                if constexpr (BIAS == 2) v += bias[m0 + row];
                if constexpr (sizeof(TOUT) == 2)
                    Cb[(long)row * ldc + col] = to_bf16(v);
                else
                    Cb[(long)row * ldc + col] = v;
            }
        }
    }
}

// fp32 -> bf16, 8 elems/thread
__global__ __launch_bounds__(256)
void cvt_f32_bf16(const float* __restrict__ src, short* __restrict__ dst, int n8)
{
    int i = blockIdx.x * 256 + threadIdx.x;
    if (i < n8) {
        float4 a = ((const float4*)src)[2 * i];
        float4 b = ((const float4*)src)[2 * i + 1];
        bf16x8 o = { to_bf16(a.x), to_bf16(a.y), to_bf16(a.z), to_bf16(a.w),
                     to_bf16(b.x), to_bf16(b.y), to_bf16(b.z), to_bf16(b.w) };
        *(bf16x8*)&dst[i * 8] = o;
    }
}

// three fp32 srcs -> contiguous bf16 dst (blockIdx.y selects src)
__global__ __launch_bounds__(256)
void cvt3_f32_bf16(const float* __restrict__ s0, const float* __restrict__ s1,
                   const float* __restrict__ s2, short* __restrict__ dst, int n8)
{
    int zz = blockIdx.y;
    const float* src = (zz == 0) ? s0 : (zz == 1) ? s1 : s2;
    int i = blockIdx.x * 256 + threadIdx.x;
    if (i < n8) {
        float4 a = ((const float4*)src)[2 * i];
        float4 b = ((const float4*)src)[2 * i + 1];
        bf16x8 o = { to_bf16(a.x), to_bf16(a.y), to_bf16(a.z), to_bf16(a.w),
                     to_bf16(b.x), to_bf16(b.y), to_bf16(b.z), to_bf16(b.w) };
        *(bf16x8*)&dst[(long)zz * n8 * 8 + i * 8] = o;
    }
}

// In-place row softmax over bf16 rows of length 2048. One block/row.
__global__ __launch_bounds__(256)
void softmax_rows(short* __restrict__ S, int ncols)
{
    const long row = blockIdx.x;
    short* p = S + row * (long)ncols;
    const int t = threadIdx.x;

    union { bf16x8 v; short s[8]; } u;
    u.v = *(const bf16x8*)&p[t * 8];
    float f[8];
    float m = -3.0e38f;
    #pragma unroll
    for (int j = 0; j < 8; ++j) { f[j] = from_bf16(u.s[j]); m = fmaxf(m, f[j]); }
    #pragma unroll
    for (int off = 32; off > 0; off >>= 1) m = fmaxf(m, __shfl_xor(m, off));

    __shared__ float red[8];
    const int wave = t >> 6;
    if ((t & 63) == 0) red[wave] = m;
    __syncthreads();
    m = fmaxf(fmaxf(red[0], red[1]), fmaxf(red[2], red[3]));

    float sum = 0.f;
    #pragma unroll
    for (int j = 0; j < 8; ++j) { f[j] = __expf(f[j] - m); sum += f[j]; }
    #pragma unroll
    for (int off = 32; off > 0; off >>= 1) sum += __shfl_xor(sum, off);
    if ((t & 63) == 0) red[4 + wave] = sum;
    __syncthreads();
    sum = red[4] + red[5] + red[6] + red[7];

    const float inv = 1.0f / sum;
    #pragma unroll
    for (int j = 0; j < 8; ++j) u.s[j] = to_bf16(f[j] * inv);
    *(bf16x8*)&p[t * 8] = u.v;
}

extern "C" void kernel_launch(void* const* d_in, const int* in_sizes, int n_in,
                              void* d_out, int out_size, void* d_ws, size_t ws_size,
                              hipStream_t stream)
{
    (void)in_sizes; (void)n_in; (void)out_size; (void)ws_size;

    const float* x  = (const float*)d_in[0];
    const float* Wq = (const float*)d_in[1];
    const float* bq = (const float*)d_in[2];
    const float* Wk = (const float*)d_in[3];
    const float* bk = (const float*)d_in[4];
    const float* Wv = (const float*)d_in[5];
    const float* bv = (const float*)d_in[6];
    float* out = (float*)d_out;

    const int S = 2048, E = 1024;
    const long M1 = 1024l * 1024;

    // ws regions (shorts)
    short* w  = (short*)d_ws;
    short* Q  = w;                  // [4][2048][1024]  (16MB)
    short* Kb = w + 8 * M1;         // [4][2048][1024]  (16MB)
    short* P  = w + 16 * M1;        // [4][2048][2048]  (32MB)
    short* VT = w + 8 * M1;         // [4][1024][2048]  over dead K (post-scores)

    // d_out scratch (last read by VT-GEMM, dead before PV writes d_out)
    short* dows = (short*)d_out;
    short* xb = dows;               // [8192][1024] bf16 (16MB)
    short* Wb = dows + 8 * M1;      // Wq,Wk,Wv bf16 (3 x 2MB)

    dim3 blk(256);

    // 1. convert inputs to bf16
    cvt_f32_bf16<<<dim3(4096), blk, 0, stream>>>(x, xb, (int)M1);
    cvt3_f32_bf16<<<dim3(512, 3), blk, 0, stream>>>(Wq, Wk, Wv, Wb, (int)(M1 / 8));

    // 2. Q,K projections (M=8192, N=1024, K=1024): grid 4x64x2 = 512 blocks
    gemm8<128, 256, 1, short><<<dim3(4, 64, 2), blk, 0, stream>>>(
        xb, E, 0, Wb, E, M1, bq, bk, nullptr, Q, Kb, nullptr, E, 0, E, 1.0f);

    // 3. scores: P[z] = Q[z] K[z]^T / 32 (M=N=2048, K=1024): 8x16x4 = 512
    gemm8<128, 256, 0, short><<<dim3(8, 16, 4), blk, 0, stream>>>(
        Q, E, 2 * M1, Kb, E, 2 * M1, nullptr, nullptr, nullptr,
        P, P, P, S, 4 * M1, E, 0.03125f);

    // 4. VT[z] = Wv xb[z]^T + bv (row bias)  (M=1024, N=2048, K=1024)
    //    into ws over dead K: grid 8x8x4 = 256 blocks
    gemm8<128, 256, 2, short><<<dim3(8, 8, 4), blk, 0, stream>>>(
        Wb + 2 * M1, E, 0, xb, E, 2 * M1, bv, nullptr, nullptr,
        VT, VT, VT, S, 2 * M1, E, 1.0f);

    // 5. softmax rows in place
    softmax_rows<<<dim3(4 * S), blk, 0, stream>>>(P, S);

    // 6. out[z] = P[z] VT[z]^T (M=2048, N=1024, K=2048): 4x16x4 = 256, fp32
    gemm8<128, 256, 0, float><<<dim3(4, 16, 4), blk, 0, stream>>>(
        P, S, 4 * M1, VT, S, 2 * M1, nullptr, nullptr, nullptr,
        out, out, out, E, 2 * M1, S, 1.0f);
}